// Round 2
// baseline (693.434 us; speedup 1.0000x reference)
//
#include <hip/hip_runtime.h>

// VQ nearest-embedding, fp32 baseline.
// score_k = 0.5*||e_k||^2 - x.e_k  (argmin same as squared L2)
// Block: 64 rows (n) x 256 codes (k-chunk), D staged in 32-slices via LDS.
// Per-thread micro-tile: 4n x 16k = 64 FMA per 5 ds_read_b128.

#define D_DIM 256
#define K_DIM 1024
#define HW_ 1024
#define NT 64
#define KT 256
#define DSTEP 32

__global__ __launch_bounds__(256) void vq_norms(const float* __restrict__ emb,
                                                float* __restrict__ nh) {
  int k = blockIdx.x * 256 + threadIdx.x;
  float s = 0.f;
#pragma unroll 8
  for (int d = 0; d < D_DIM; ++d) {
    float v = emb[d * K_DIM + k];
    s = fmaf(v, v, s);
  }
  nh[k] = 0.5f * s;
}

__global__ __launch_bounds__(256, 3) void vq_main(
    const float* __restrict__ x, const float* __restrict__ emb,
    const float* __restrict__ nh, float* __restrict__ out,
    float* __restrict__ aout) {
  __shared__ float x_lds[DSTEP][NT];   // 8 KiB, d-major
  __shared__ float e_lds[DSTEP][KT];   // 32 KiB, d-major

  const int t = threadIdx.x;
  const int tx = t & 15;   // k direction (16 threads)
  const int ty = t >> 4;   // n direction (16 groups of 4 rows)
  const int n0 = blockIdx.x * NT;
  const int b = n0 >> 10;           // 64 rows always within one b (64 | 1024)
  const int hw0 = n0 & (HW_ - 1);
  const float* xb = x + ((size_t)b * D_DIM) * HW_ + hw0;

  float bestv[4];
  int bestk[4];
#pragma unroll
  for (int i = 0; i < 4; ++i) { bestv[i] = 3.4e38f; bestk[i] = 0; }

  for (int kc = 0; kc < K_DIM / KT; ++kc) {
    float acc[4][16];
#pragma unroll
    for (int i = 0; i < 4; ++i)
#pragma unroll
      for (int j = 0; j < 16; ++j) acc[i][j] = 0.f;

    for (int ds = 0; ds < D_DIM / DSTEP; ++ds) {
      const int d0 = ds * DSTEP;
      __syncthreads();  // previous stage's readers done before overwrite
      // stage x tile: 32 d-rows x 64 n, coalesced float4
#pragma unroll
      for (int it = 0; it < 2; ++it) {
        int idx = t + it * 256;          // 0..511 = 32 rows * 16 float4
        int dr = idx >> 4, c4 = idx & 15;
        float4 v = *(const float4*)(xb + (size_t)(d0 + dr) * HW_ + c4 * 4);
        *(float4*)&x_lds[dr][c4 * 4] = v;
      }
      // stage e tile: 32 d-rows x 256 k, coalesced float4
#pragma unroll
      for (int it = 0; it < 8; ++it) {
        int idx = t + it * 256;          // 0..2047 = 32 rows * 64 float4
        int dr = idx >> 6, c4 = idx & 63;
        float4 v =
            *(const float4*)(emb + (size_t)(d0 + dr) * K_DIM + kc * KT + c4 * 4);
        *(float4*)&e_lds[dr][c4 * 4] = v;
      }
      __syncthreads();
#pragma unroll 4
      for (int dd = 0; dd < DSTEP; ++dd) {
        float4 xv4 = *(const float4*)&x_lds[dd][ty * 4];
        float xv[4] = {xv4.x, xv4.y, xv4.z, xv4.w};
        float ev[16];
#pragma unroll
        for (int j = 0; j < 4; ++j) {
          // per-thread k set: tx*4 + 64*j (+q) — 16B-stride addrs => 2-way banks (free)
          float4 e4 = *(const float4*)&e_lds[dd][j * 64 + tx * 4];
          ev[4 * j + 0] = e4.x;
          ev[4 * j + 1] = e4.y;
          ev[4 * j + 2] = e4.z;
          ev[4 * j + 3] = e4.w;
        }
#pragma unroll
        for (int i = 0; i < 4; ++i)
#pragma unroll
          for (int j = 0; j < 16; ++j)
            acc[i][j] = fmaf(xv[i], ev[j], acc[i][j]);
      }
    }
    // fold this k-chunk into running best (k ascending => first-min tie-break)
#pragma unroll
    for (int j = 0; j < 4; ++j)
#pragma unroll
      for (int q = 0; q < 4; ++q) {
        int k = kc * KT + j * 64 + tx * 4 + q;
        float nhv = nh[k];
#pragma unroll
        for (int i = 0; i < 4; ++i) {
          float s = nhv - acc[i][4 * j + q];
          if (s < bestv[i]) {
            bestv[i] = s;
            bestk[i] = k;
          }
        }
      }
  }

  __syncthreads();  // all LDS compute reads done before x_lds reuse
  int* bk = (int*)&x_lds[0][0];
  // reduce across the 16 tx lanes holding the same rows (lanes t%16)
#pragma unroll
  for (int i = 0; i < 4; ++i) {
    float v = bestv[i];
    int k = bestk[i];
#pragma unroll
    for (int off = 8; off > 0; off >>= 1) {
      float ov = __shfl_xor(v, off, 16);
      int ok = __shfl_xor(k, off, 16);
      if (ov < v || (ov == v && ok < k)) {
        v = ov;
        k = ok;
      }
    }
    if (tx == 0) bk[ty * 4 + i] = k;
  }
  __syncthreads();

  // output 1: argmin as float (harness reads whole d_out as f32)
  if (t < NT) aout[n0 + t] = (float)bk[t];

  // output 0: gather winning codes, write coalesced across n
#pragma unroll 4
  for (int it = 0; it < 64; ++it) {
    int idx = t + it * 256;  // 64 n * 256 d
    int nl = idx & 63, d = idx >> 6;
    out[(size_t)(b * D_DIM + d) * HW_ + hw0 + nl] = emb[d * K_DIM + bk[nl]];
  }
}

extern "C" void kernel_launch(void* const* d_in, const int* in_sizes, int n_in,
                              void* d_out, int out_size, void* d_ws,
                              size_t ws_size, hipStream_t stream) {
  const float* x = (const float*)d_in[0];
  const float* emb = (const float*)d_in[1];
  float* out = (float*)d_out;
  float* aout = out + (size_t)64 * 256 * 32 * 32;  // 16777216
  float* nh = (float*)d_ws;                        // 1024 floats
  vq_norms<<<K_DIM / 256, 256, 0, stream>>>(emb, nh);
  vq_main<<<(64 * 32 * 32) / NT, 256, 0, stream>>>(x, emb, nh, out, aout);
}

// Round 3
// 238.748 us; speedup vs baseline: 2.9045x; 2.9045x over previous
//
#include <hip/hip_runtime.h>

// VQ nearest-embedding via 3-pass fp16-split MFMA.
// score_k = 0.5*||e_k||^2 - x.e_k ; x.e = xh.eh + xl.eh + xh.el (+ ~2e-7)
// A = codes (M), B = x-rows (N), 16x16x32_f16: C/D col = lane&15 = x-row
// -> per-lane argmin fold. LDS 16B-block XOR swizzle on both operands.

typedef _Float16 half8 __attribute__((ext_vector_type(8)));
typedef _Float16 half2t __attribute__((ext_vector_type(2)));
typedef float f32x4 __attribute__((ext_vector_type(4)));

#define D_DIM 256
#define K_DIM 1024
#define HW_ 1024
#define NROWS 64   // rows per block
#define KC_SZ 256  // codes per kc chunk
#define DS_SZ 32   // d per chunk

__global__ __launch_bounds__(256) void vq_prep(const float* __restrict__ emb,
                                               float* __restrict__ nh,
                                               _Float16* __restrict__ eh,
                                               _Float16* __restrict__ el) {
  int gt = blockIdx.x * 256 + threadIdx.x;  // 16384 threads = 1024 k x 16
  int k = gt >> 4;
  int d0 = (gt & 15) * 16;
  half8 h0, h1, l0, l1;
  float s = 0.f;
#pragma unroll
  for (int j = 0; j < 16; ++j) {
    float v = emb[(size_t)(d0 + j) * K_DIM + k];
    _Float16 h = (_Float16)v;
    _Float16 lo = (_Float16)(v - (float)h);
    if (j < 8) { h0[j] = h; l0[j] = lo; }
    else       { h1[j - 8] = h; l1[j - 8] = lo; }
    s = fmaf(v, v, s);
  }
  *(half8*)(eh + (size_t)k * D_DIM + d0) = h0;
  *(half8*)(eh + (size_t)k * D_DIM + d0 + 8) = h1;
  *(half8*)(el + (size_t)k * D_DIM + d0) = l0;
  *(half8*)(el + (size_t)k * D_DIM + d0 + 8) = l1;
#pragma unroll
  for (int off = 1; off < 16; off <<= 1) s += __shfl_xor(s, off, 16);
  if ((gt & 15) == 0) nh[k] = 0.5f * s;
}

__global__ __launch_bounds__(256, 2) void vq_mfma(
    const float* __restrict__ x, const float* __restrict__ emb,
    const float* __restrict__ nh, const _Float16* __restrict__ eh,
    const _Float16* __restrict__ el, float* __restrict__ out,
    float* __restrict__ aout) {
  // rows of 32 halfs (64B); 16B-block swizzle: phys_blk = logical_g ^ ((row>>2)&3)
  __shared__ __align__(16) _Float16 ehh[KC_SZ * DS_SZ];  // 16 KiB
  __shared__ __align__(16) _Float16 ehl[KC_SZ * DS_SZ];  // 16 KiB
  __shared__ __align__(16) _Float16 xhh[NROWS * DS_SZ];  // 4 KiB
  __shared__ __align__(16) _Float16 xhl[NROWS * DS_SZ];  // 4 KiB
  __shared__ float nh_s[KC_SZ];
  __shared__ float redv[4][NROWS];
  __shared__ int redk[4][NROWS];
  __shared__ int bk_s[NROWS];

  const int t = threadIdx.x;
  const int w = t >> 6, l = t & 63, c = l & 15, g = l >> 4;
  const int n0 = blockIdx.x * NROWS;
  const int b = n0 >> 10, hw0 = n0 & (HW_ - 1);
  const float* xb = x + (size_t)b * D_DIM * HW_ + hw0;

  float bestv[4];
  int bestk[4];
#pragma unroll
  for (int i = 0; i < 4; ++i) { bestv[i] = 3.4e38f; bestk[i] = 0; }

  // per-lane frag offsets (in _Float16 elements): row*32 + swz_block*8
  const int swz8 = (g ^ ((c >> 2) & 3)) * 8;
  const int a_elem = (w * 64 + c) * 32 + swz8;  // + ta*512
  const int b_elem = c * 32 + swz8;             // + tb*512

  const int dp = t >> 4, n4 = (t & 15) * 4;  // x-staging role

  for (int kc = 0; kc < 4; ++kc) {
    f32x4 acc[4][4];
#pragma unroll
    for (int i = 0; i < 4; ++i)
#pragma unroll
      for (int j = 0; j < 4; ++j) acc[i][j] = (f32x4)0.f;

    for (int ds = 0; ds < 8; ++ds) {
      __syncthreads();  // previous readers done before overwrite
      if (ds == 0) nh_s[t] = nh[kc * KC_SZ + t];
      // ---- stage e hi/lo (straight swizzled copy from pre-transposed ws)
      const size_t esrc = (size_t)(kc * KC_SZ) * D_DIM + ds * DS_SZ;
#pragma unroll
      for (int it = 0; it < 4; ++it) {
        int flat = it * 256 + t;  // 0..1023 16B-chunks
        int cc = flat >> 2, q = flat & 3;
        int wq = q ^ ((cc >> 2) & 3);
        ((half8*)ehh)[cc * 4 + wq] =
            *(const half8*)(eh + esrc + (size_t)cc * D_DIM + q * 8);
        ((half8*)ehl)[cc * 4 + wq] =
            *(const half8*)(el + esrc + (size_t)cc * D_DIM + q * 8);
      }
      // ---- stage x: transpose + fp16 hi/lo split (d=2dp,2dp+1 ; n=n4..n4+3)
      {
        const float* xs = xb + (size_t)(ds * DS_SZ + 2 * dp) * HW_;
        float4 fa = *(const float4*)(xs + n4);
        float4 fb = *(const float4*)(xs + HW_ + n4);
        float av[4] = {fa.x, fa.y, fa.z, fa.w};
        float bv[4] = {fb.x, fb.y, fb.z, fb.w};
#pragma unroll
        for (int j = 0; j < 4; ++j) {
          int n = n4 + j;
          int idx = n * 32 + ((dp >> 2) ^ ((n >> 2) & 3)) * 8 + (dp & 3) * 2;
          _Float16 ah = (_Float16)av[j];
          _Float16 al = (_Float16)(av[j] - (float)ah);
          _Float16 bh = (_Float16)bv[j];
          _Float16 bl = (_Float16)(bv[j] - (float)bh);
          half2t hv; hv[0] = ah; hv[1] = bh;
          half2t lv; lv[0] = al; lv[1] = bl;
          *(half2t*)&xhh[idx] = hv;
          *(half2t*)&xhl[idx] = lv;
        }
      }
      __syncthreads();
      // ---- fragments
      half8 Ah[4], Al[4], Bh[4], Bl[4];
#pragma unroll
      for (int ta = 0; ta < 4; ++ta) {
        Ah[ta] = *(const half8*)&ehh[a_elem + ta * 512];
        Al[ta] = *(const half8*)&ehl[a_elem + ta * 512];
      }
#pragma unroll
      for (int tb = 0; tb < 4; ++tb) {
        Bh[tb] = *(const half8*)&xhh[b_elem + tb * 512];
        Bl[tb] = *(const half8*)&xhl[b_elem + tb * 512];
      }
      // ---- 3-pass MFMA
#pragma unroll
      for (int ta = 0; ta < 4; ++ta)
#pragma unroll
        for (int tb = 0; tb < 4; ++tb) {
          acc[ta][tb] = __builtin_amdgcn_mfma_f32_16x16x32_f16(
              Ah[ta], Bh[tb], acc[ta][tb], 0, 0, 0);
          acc[ta][tb] = __builtin_amdgcn_mfma_f32_16x16x32_f16(
              Al[ta], Bh[tb], acc[ta][tb], 0, 0, 0);
          acc[ta][tb] = __builtin_amdgcn_mfma_f32_16x16x32_f16(
              Ah[ta], Bl[tb], acc[ta][tb], 0, 0, 0);
        }
    }
    // ---- fold: per-lane argmin (codes ascend with kc,ta,r => first-min ties)
#pragma unroll
    for (int ta = 0; ta < 4; ++ta) {
      f32x4 nh4 = *(const f32x4*)&nh_s[w * 64 + ta * 16 + 4 * g];
#pragma unroll
      for (int r = 0; r < 4; ++r) {
        int code = kc * KC_SZ + w * 64 + ta * 16 + 4 * g + r;
#pragma unroll
        for (int tb = 0; tb < 4; ++tb) {
          float s = nh4[r] - acc[ta][tb][r];
          if (s < bestv[tb]) { bestv[tb] = s; bestk[tb] = code; }
        }
      }
    }
  }

  // cross-lane: combine the 4 g-groups (same x-row, disjoint codes)
#pragma unroll
  for (int tb = 0; tb < 4; ++tb) {
    float v = bestv[tb];
    int k = bestk[tb];
#pragma unroll
    for (int off = 16; off <= 32; off <<= 1) {
      float ov = __shfl_xor(v, off);
      int ok = __shfl_xor(k, off);
      if (ov < v || (ov == v && ok < k)) { v = ov; k = ok; }
    }
    if (g == 0) { redv[w][tb * 16 + c] = v; redk[w][tb * 16 + c] = k; }
  }
  __syncthreads();
  if (t < NROWS) {  // combine the 4 waves (disjoint codes, same rows)
    float v = redv[0][t];
    int k = redk[0][t];
#pragma unroll
    for (int w2 = 1; w2 < 4; ++w2) {
      float ov = redv[w2][t];
      int ok = redk[w2][t];
      if (ov < v || (ov == v && ok < k)) { v = ov; k = ok; }
    }
    bk_s[t] = k;
    aout[n0 + t] = (float)k;  // output 1: argmin as f32
  }
  __syncthreads();
  // output 0: gather winning codes (bit-exact emb copies), coalesced in n
  const int myk = bk_s[l];
#pragma unroll 4
  for (int it = 0; it < 64; ++it) {
    int d = w + it * 4;
    out[((size_t)b * D_DIM + d) * HW_ + hw0 + l] = emb[(size_t)d * K_DIM + myk];
  }
}

extern "C" void kernel_launch(void* const* d_in, const int* in_sizes, int n_in,
                              void* d_out, int out_size, void* d_ws,
                              size_t ws_size, hipStream_t stream) {
  const float* x = (const float*)d_in[0];
  const float* emb = (const float*)d_in[1];
  float* out = (float*)d_out;
  float* aout = out + (size_t)64 * 256 * 32 * 32;  // 16777216
  float* nh = (float*)d_ws;                        // 4 KiB
  _Float16* eh = (_Float16*)((char*)d_ws + 4096);  // 512 KiB
  _Float16* el = eh + (size_t)K_DIM * D_DIM;       // 512 KiB
  vq_prep<<<64, 256, 0, stream>>>(emb, nh, eh, el);
  vq_mfma<<<(64 * 32 * 32) / NROWS, 256, 0, stream>>>(x, emb, nh, eh, el, out,
                                                      aout);
}

// Round 4
// 235.053 us; speedup vs baseline: 2.9501x; 1.0157x over previous
//
#include <hip/hip_runtime.h>

// VQ nearest-embedding, 3-pass fp16-split MFMA (32x32x16), swizzled-LDS DMA.
// acc = x.e - 0.5*||e||^2 (init acc = -0.5||e||^2), argmax == argmin dist.
// A = codes, B = x-rows; C/D: col=lane&31 (x-row), row=(reg&3)+8*(reg>>2)+4*(lane>>5).
// LDS tiles [row][32 halfs] in paired-row layout: 2 rows per 128B group,
// 16B-block phys = (((row&1)<<2)|dblk) ^ ((row>>1)&7)  -> conflict-free b128.

typedef _Float16 half8 __attribute__((ext_vector_type(8)));
typedef float f32x16 __attribute__((ext_vector_type(16)));
typedef unsigned int u32;
typedef const __attribute__((address_space(1))) u32* gp_t;
typedef __attribute__((address_space(3))) u32* lp_t;

#define K_DIM 1024
#define D_DIM 256

__device__ __forceinline__ int swz16(int row, int dblk) {
  return (row >> 1) * 128 + (((((row & 1) << 2) | dblk)) ^ ((row >> 1) & 7)) * 16;
}

// emb (f32 [256 d][1024 k]) -> nh (0.5*||e||^2, via atomics) + fp16 hi/lo
// tile images [tile=kc*8+ds][256 codes][32 d] in the swizzled LDS byte order.
__global__ __launch_bounds__(256) void vq_prep(const float* __restrict__ emb,
                                               float* __restrict__ nh,
                                               char* __restrict__ eimg_h,
                                               char* __restrict__ eimg_l) {
  __shared__ float tile[32][68];
  const int t = threadIdx.x;
  const int di = blockIdx.x & 7, ki = blockIdx.x >> 3;  // d-tile(32), k-tile(64)
  const int d0 = di * 32, k0 = ki * 64;
#pragma unroll
  for (int r = 0; r < 2; ++r) {
    int slot = t + r * 256;
    int dr = slot >> 4, c4 = slot & 15;
    float4 v = *(const float4*)(emb + (size_t)(d0 + dr) * K_DIM + k0 + c4 * 4);
    *(float4*)&tile[dr][c4 * 4] = v;
  }
  __syncthreads();
  const int codeL = t >> 2, blk = t & 3;
  const int code = k0 + codeL;
  half8 hh, ll;
  float s = 0.f;
#pragma unroll
  for (int j = 0; j < 8; ++j) {
    float v = tile[blk * 8 + j][codeL];
    _Float16 h = (_Float16)v;
    hh[j] = h;
    ll[j] = (_Float16)(v - (float)h);
    s = fmaf(v, v, s);
  }
  const size_t base = (size_t)((code >> 8) * 8 + di) * 16384;
  const int off = swz16(code & 255, blk);
  *(half8*)(eimg_h + base + off) = hh;
  *(half8*)(eimg_l + base + off) = ll;
  s += __shfl_xor(s, 1);
  s += __shfl_xor(s, 2);
  if ((t & 3) == 0) atomicAdd(&nh[code], 0.5f * s);
}

#define STAGE_E(tidx, bufsel)                                                 \
  {                                                                           \
    const size_t tb = (size_t)(tidx) * 16384;                                 \
    _Pragma("unroll") for (int r = 0; r < 2; ++r) {                           \
      const int o = r * 8192 + w * 1024;                                      \
      __builtin_amdgcn_global_load_lds((gp_t)(eimg_h + tb + o + l * 16),      \
                                       (lp_t)(eh_lds[bufsel] + o), 16, 0, 0); \
      __builtin_amdgcn_global_load_lds((gp_t)(eimg_l + tb + o + l * 16),      \
                                       (lp_t)(el_lds[bufsel] + o), 16, 0, 0); \
    }                                                                         \
  }

#define X_CONVERT_WRITE(bufsel)                                               \
  {                                                                           \
    half8 h0, h1, l0, l1;                                                     \
    _Pragma("unroll") for (int j = 0; j < 8; ++j) {                           \
      _Float16 a = (_Float16)xv[j].x;                                         \
      h0[j] = a;                                                              \
      l0[j] = (_Float16)(xv[j].x - (float)a);                                 \
      _Float16 c = (_Float16)xv[j].y;                                         \
      h1[j] = c;                                                              \
      l1[j] = (_Float16)(xv[j].y - (float)c);                                 \
    }                                                                         \
    *(half8*)(xh_lds[bufsel] + xw0) = h0;                                     \
    *(half8*)(xh_lds[bufsel] + xw1) = h1;                                     \
    *(half8*)(xl_lds[bufsel] + xw0) = l0;                                     \
    *(half8*)(xl_lds[bufsel] + xw1) = l1;                                     \
  }

__global__ __launch_bounds__(512, 2) void vq_main(
    const float* __restrict__ x, const float* __restrict__ emb,
    const float* __restrict__ nh, const char* __restrict__ eimg_h,
    const char* __restrict__ eimg_l, float* __restrict__ out,
    float* __restrict__ aout) {
  __shared__ __align__(16) char eh_lds[2][16384];
  __shared__ __align__(16) char el_lds[2][16384];
  __shared__ __align__(16) char xh_lds[2][16384];
  __shared__ __align__(16) char xl_lds[2][16384];
  __shared__ float nh_s[1024];

  const int t = threadIdx.x;
  const int w = t >> 6, l = t & 63;
  const int mw = w & 1, nw = w >> 1;       // waves: 2 code-halves x 4 row-quads
  const int lr = l & 31, lhi = l >> 5;
  const int b = blockIdx.x >> 2;
  const int hw0 = (blockIdx.x & 3) * 256;
  const float* xb = x + (size_t)b * D_DIM * K_DIM + hw0;

  // x staging role: thread -> rows {2*n2s, 2*n2s+1}, d = dgrp*8..+7
  const int n2s = t & 127, dgrp = t >> 7;
  const int xw0 = n2s * 128 + ((dgrp) ^ (n2s & 7)) * 16;
  const int xw1 = n2s * 128 + ((4 | dgrp) ^ (n2s & 7)) * 16;

  // fragment byte offsets
  int offA[4][2], offB[2][2];
#pragma unroll
  for (int Mt = 0; Mt < 4; ++Mt)
#pragma unroll
    for (int ks = 0; ks < 2; ++ks)
      offA[Mt][ks] = swz16(mw * 128 + Mt * 32 + lr, ks * 2 + lhi);
#pragma unroll
  for (int Nt = 0; Nt < 2; ++Nt)
#pragma unroll
    for (int ks = 0; ks < 2; ++ks)
      offB[Nt][ks] = swz16(nw * 64 + Nt * 32 + lr, ks * 2 + lhi);

  // prologue: nh -> LDS; stage tile 0 into buffer 0
  nh_s[t] = nh[t];
  nh_s[t + 512] = nh[t + 512];
  {
    float2 xv[8];
#pragma unroll
    for (int j = 0; j < 8; ++j)
      xv[j] = *(const float2*)(xb + (size_t)(dgrp * 8 + j) * K_DIM + 2 * n2s);
    STAGE_E(0, 0);
    X_CONVERT_WRITE(0);
  }
  __syncthreads();

  float bestv[2] = {-3.4e38f, -3.4e38f};
  int bestk[2] = {0, 0};

  for (int kc = 0; kc < 4; ++kc) {
    f32x16 acc[4][2];
#pragma unroll
    for (int Mt = 0; Mt < 4; ++Mt)
#pragma unroll
      for (int reg = 0; reg < 16; ++reg) {
        int code = kc * 256 + mw * 128 + Mt * 32 + (reg & 3) + 8 * (reg >> 2) +
                   4 * lhi;
        float nv = -nh_s[code];
        acc[Mt][0][reg] = nv;
        acc[Mt][1][reg] = nv;
      }
#pragma unroll 2
    for (int ds = 0; ds < 8; ++ds) {
      const int ti = kc * 8 + ds;
      const int buf = ti & 1, bufn = buf ^ 1;
      const int tn = (ti + 1) & 31;
      // issue next-tile x loads (regs) and e DMA (direct to LDS) up front
      float2 xv[8];
      const int dsn = tn & 7;
#pragma unroll
      for (int j = 0; j < 8; ++j)
        xv[j] = *(const float2*)(xb + (size_t)(dsn * 32 + dgrp * 8 + j) * K_DIM +
                                 2 * n2s);
      STAGE_E(tn, bufn);
      // compute current tile
#pragma unroll
      for (int ks = 0; ks < 2; ++ks) {
        half8 Ah[4], Al[4], Bh[2], Bl[2];
#pragma unroll
        for (int Mt = 0; Mt < 4; ++Mt) {
          Ah[Mt] = *(const half8*)(eh_lds[buf] + offA[Mt][ks]);
          Al[Mt] = *(const half8*)(el_lds[buf] + offA[Mt][ks]);
        }
#pragma unroll
        for (int Nt = 0; Nt < 2; ++Nt) {
          Bh[Nt] = *(const half8*)(xh_lds[buf] + offB[Nt][ks]);
          Bl[Nt] = *(const half8*)(xl_lds[buf] + offB[Nt][ks]);
        }
#pragma unroll
        for (int Mt = 0; Mt < 4; ++Mt)
#pragma unroll
          for (int Nt = 0; Nt < 2; ++Nt) {
            acc[Mt][Nt] = __builtin_amdgcn_mfma_f32_32x32x16_f16(
                Ah[Mt], Bh[Nt], acc[Mt][Nt], 0, 0, 0);
            acc[Mt][Nt] = __builtin_amdgcn_mfma_f32_32x32x16_f16(
                Al[Mt], Bh[Nt], acc[Mt][Nt], 0, 0, 0);
            acc[Mt][Nt] = __builtin_amdgcn_mfma_f32_32x32x16_f16(
                Ah[Mt], Bl[Nt], acc[Mt][Nt], 0, 0, 0);
          }
      }
      // convert & write next x tile, then sync (drains e-DMA; ~fully landed)
      X_CONVERT_WRITE(bufn);
      __syncthreads();
    }
    // fold (argmax, ties -> smaller code == reference first-min)
#pragma unroll
    for (int Mt = 0; Mt < 4; ++Mt)
#pragma unroll
      for (int reg = 0; reg < 16; ++reg) {
        int code = kc * 256 + mw * 128 + Mt * 32 + (reg & 3) + 8 * (reg >> 2) +
                   4 * lhi;
#pragma unroll
        for (int Nt = 0; Nt < 2; ++Nt) {
          float v = acc[Mt][Nt][reg];
          if (v > bestv[Nt] || (v == bestv[Nt] && code < bestk[Nt])) {
            bestv[Nt] = v;
            bestk[Nt] = code;
          }
        }
      }
  }

  // epilogue: reuse xh_lds[0] as scratch (loop done, synced below)
  float* redv = (float*)&xh_lds[0][0];   // [2][256]
  int* redk = (int*)&xh_lds[0][2048];    // [2][256]
  int* bk_s = (int*)&xh_lds[0][4096];    // [256]
#pragma unroll
  for (int Nt = 0; Nt < 2; ++Nt) {
    float v = bestv[Nt];
    int k = bestk[Nt];
    float ov = __shfl_xor(v, 32);
    int ok = __shfl_xor(k, 32);
    if (ov > v || (ov == v && ok < k)) { v = ov; k = ok; }
    if (lhi == 0) {
      int row = nw * 64 + Nt * 32 + lr;
      redv[mw * 256 + row] = v;
      redk[mw * 256 + row] = k;
    }
  }
  __syncthreads();
  if (t < 256) {
    float v0 = redv[t], v1 = redv[256 + t];
    int k0 = redk[t], k1 = redk[256 + t];
    int k = (v1 > v0 || (v1 == v0 && k1 < k0)) ? k1 : k0;
    bk_s[t] = k;
    aout[blockIdx.x * 256 + t] = (float)k;
  }
  __syncthreads();
  // gather winning codes (bit-exact f32 emb), coalesced in n
  const int n = t & 255, dh = t >> 8;
#pragma unroll 4
  for (int it = 0; it < 128; ++it) {
    int d = it * 2 + dh;
    out[((size_t)b * D_DIM + d) * K_DIM + hw0 + n] =
        emb[(size_t)d * K_DIM + bk_s[n]];
  }
}

extern "C" void kernel_launch(void* const* d_in, const int* in_sizes, int n_in,
                              void* d_out, int out_size, void* d_ws,
                              size_t ws_size, hipStream_t stream) {
  const float* x = (const float*)d_in[0];
  const float* emb = (const float*)d_in[1];
  float* out = (float*)d_out;
  float* aout = out + (size_t)64 * 256 * 32 * 32;  // 16777216
  float* nh = (float*)d_ws;                        // 4 KiB (atomics, zeroed)
  char* eimg_h = (char*)d_ws + 4096;               // 512 KiB
  char* eimg_l = eimg_h + 524288;                  // 512 KiB
  hipMemsetAsync(nh, 0, 4096, stream);
  vq_prep<<<128, 256, 0, stream>>>(emb, nh, eimg_h, eimg_l);
  vq_main<<<256, 512, 0, stream>>>(x, emb, nh, eimg_h, eimg_l, out, aout);
}

// Round 5
// 229.501 us; speedup vs baseline: 3.0215x; 1.0242x over previous
//
#include <hip/hip_runtime.h>

// VQ nearest-embedding, flash-style: x persistent in registers, e streamed.
// score = x.e - 0.5||e||^2 (acc init = -0.5||e||^2), argmax == argmin dist.
// MFMA 32x32x16_f16, 3-pass hi/lo split (exact to ~2e-7).
// A = codes (from LDS, DMA-staged pre-swizzled images), B = x-rows (registers).
// A-frag: lane l -> code_local = Mt*32+(l&31), d-block = ks*2+(l>>5) (8 halfs).
// C/D: col = lane&31 = x-row, row = (reg&3)+8*(reg>>2)+4*(lane>>5) = code_local.
// e image layout (16B units): tile*2048 + code*32 + ((dblk)^(code&31)); the
// XOR makes frag ds_read_b128 conflict-free; DMA copies image linearly.

typedef _Float16 half8 __attribute__((ext_vector_type(8)));
typedef float f32x4v __attribute__((ext_vector_type(4)));
typedef float f32x16 __attribute__((ext_vector_type(16)));
typedef const __attribute__((address_space(1))) unsigned int* gp_t;
typedef __attribute__((address_space(3))) unsigned int* lp_t;

#define K_DIM 1024
#define D_DIM 256

// emb f32 [256 d][1024 k] -> per-di partial norms nhp[8][1024] + fp16 hi/lo
// images in the exact main-loop LDS byte order. Fully coalesced, no atomics.
__global__ __launch_bounds__(256) void vq_prep(const float* __restrict__ emb,
                                               float* __restrict__ nhp,
                                               char* __restrict__ eimg_h,
                                               char* __restrict__ eimg_l) {
  __shared__ float tile[32][66];
  const int t = threadIdx.x;
  const int ki = blockIdx.x >> 3, di = blockIdx.x & 7;
  const int d0 = di * 32, k0 = ki * 64;
#pragma unroll
  for (int r = 0; r < 4; ++r) {
    int slot = r * 256 + t;            // 32 d-rows x 32 float2
    int dr = slot >> 5, c2 = slot & 31;
    float2 v = *(const float2*)(emb + (size_t)(d0 + dr) * K_DIM + k0 + c2 * 2);
    *(float2*)&tile[dr][c2 * 2] = v;
  }
  __syncthreads();
  const int codeL = t >> 2, q = t & 3;  // code-local 0..63, dblk-quarter
  half8 hh, ll;
  float s = 0.f;
#pragma unroll
  for (int j = 0; j < 8; ++j) {
    float v = tile[q * 8 + j][codeL];
    _Float16 h = (_Float16)v;
    hh[j] = h;
    ll[j] = (_Float16)(v - (float)h);
    s = fmaf(v, v, s);
  }
  const int dblk = di * 4 + q;                   // 0..31
  const int phys = dblk ^ (codeL & 31);
  const size_t off = (size_t)ki * 32768 + codeL * 512 + phys * 16;
  *(half8*)(eimg_h + off) = hh;
  *(half8*)(eimg_l + off) = ll;
  s += __shfl_xor(s, 1);
  s += __shfl_xor(s, 2);
  if (q == 0) nhp[di * K_DIM + k0 + codeL] = s;  // partial over 32 d
}

#define STAGE(tile_i, bufsel)                                                \
  {                                                                          \
    const size_t tb = (size_t)(tile_i) * 32768 + w * 1024 + l * 16;          \
    _Pragma("unroll") for (int r = 0; r < 8; ++r) {                          \
      __builtin_amdgcn_global_load_lds((gp_t)(eimg_h + tb + r * 4096),       \
                                       (lp_t)(ebuf_h[bufsel] + w * 1024 +    \
                                              r * 4096),                     \
                                       16, 0, 0);                            \
      __builtin_amdgcn_global_load_lds((gp_t)(eimg_l + tb + r * 4096),       \
                                       (lp_t)(ebuf_l[bufsel] + w * 1024 +    \
                                              r * 4096),                     \
                                       16, 0, 0);                            \
    }                                                                        \
  }

__global__ __launch_bounds__(256, 1) void vq_main(
    const float* __restrict__ x, const float* __restrict__ emb,
    const float* __restrict__ nhp, const char* __restrict__ eimg_h,
    const char* __restrict__ eimg_l, float* __restrict__ out,
    float* __restrict__ aout) {
  __shared__ __align__(16) char ebuf_h[2][32768];
  __shared__ __align__(16) char ebuf_l[2][32768];
  __shared__ __align__(16) float x_lds[16][256];  // 16 KiB chunk buffer
  __shared__ float nh_s[1024];
  __shared__ int bk_s[256];

  const int t = threadIdx.x;
  const int w = t >> 6, l = t & 63, lr = l & 31, lhi = l >> 5;
  const int b = blockIdx.x >> 2;
  const int hw0 = (blockIdx.x & 3) * 256;
  const float* xb = x + (size_t)b * D_DIM * K_DIM + hw0;

  // 0.5*||e||^2 from partials (coalesced)
#pragma unroll
  for (int i = 0; i < 4; ++i) {
    int c = i * 256 + t;
    float s = 0.f;
#pragma unroll
    for (int p = 0; p < 8; ++p) s += nhp[p * K_DIM + c];
    nh_s[c] = 0.5f * s;
  }

  STAGE(0, 0);  // tile-0 DMA overlaps the x prologue

  // ---- x prologue: rows w*64..+63 of this wave -> persistent B-frags
  half8 Bh[2][16], Bl[2][16];
  for (int c = 0; c < 16; ++c) {  // 16-d chunk == one ks slice
    __syncthreads();
#pragma unroll
    for (int i = 0; i < 4; ++i) {
      int slot = i * 256 + t;  // 16 d-rows x 64 float4
      int dr = slot >> 6, c4 = slot & 63;
      float4 v = *(const float4*)(xb + (size_t)(c * 16 + dr) * K_DIM + c4 * 4);
      *(float4*)&x_lds[dr][c4 * 4] = v;
    }
    __syncthreads();
#pragma unroll
    for (int Nt = 0; Nt < 2; ++Nt) {
      int row = w * 64 + Nt * 32 + lr;
      half8 hv, lv;
#pragma unroll
      for (int j = 0; j < 8; ++j) {
        float v = x_lds[lhi * 8 + j][row];
        _Float16 h = (_Float16)v;
        hv[j] = h;
        lv[j] = (_Float16)(v - (float)h);
      }
      Bh[Nt][c] = hv;
      Bl[Nt][c] = lv;
    }
  }

  float bestv[2] = {-3.4e38f, -3.4e38f};
  int bestk[2] = {0, 0};

  // ---- tile loop: 16 tiles x 64 codes, full D per tile
  for (int ti = 0; ti < 16; ++ti) {
    const int buf = ti & 1;
    if (ti < 15) STAGE(ti + 1, buf ^ 1);
    // acc init = -0.5||e||^2 (broadcast b128 reads from nh_s)
    f32x16 acc[2][2];
#pragma unroll
    for (int Mt = 0; Mt < 2; ++Mt)
#pragma unroll
      for (int rg = 0; rg < 4; ++rg) {
        f32x4v nv = *(const f32x4v*)&nh_s[ti * 64 + Mt * 32 + rg * 8 + lhi * 4];
#pragma unroll
        for (int j = 0; j < 4; ++j) {
          acc[Mt][0][rg * 4 + j] = -nv[j];
          acc[Mt][1][rg * 4 + j] = -nv[j];
        }
      }
    // K loop: 16 ks slices, A from LDS, B from registers
#pragma unroll
    for (int ks = 0; ks < 16; ++ks) {
      const int po = ((ks * 2 + lhi) ^ lr) * 16;  // swizzled 16B block
      half8 Ah0 = *(const half8*)(ebuf_h[buf] + lr * 512 + po);
      half8 Ah1 = *(const half8*)(ebuf_h[buf] + 16384 + lr * 512 + po);
      half8 Al0 = *(const half8*)(ebuf_l[buf] + lr * 512 + po);
      half8 Al1 = *(const half8*)(ebuf_l[buf] + 16384 + lr * 512 + po);
#pragma unroll
      for (int Nt = 0; Nt < 2; ++Nt) {
        acc[0][Nt] = __builtin_amdgcn_mfma_f32_32x32x16_f16(Ah0, Bh[Nt][ks],
                                                            acc[0][Nt], 0, 0, 0);
        acc[1][Nt] = __builtin_amdgcn_mfma_f32_32x32x16_f16(Ah1, Bh[Nt][ks],
                                                            acc[1][Nt], 0, 0, 0);
      }
#pragma unroll
      for (int Nt = 0; Nt < 2; ++Nt) {
        acc[0][Nt] = __builtin_amdgcn_mfma_f32_32x32x16_f16(Al0, Bh[Nt][ks],
                                                            acc[0][Nt], 0, 0, 0);
        acc[1][Nt] = __builtin_amdgcn_mfma_f32_32x32x16_f16(Al1, Bh[Nt][ks],
                                                            acc[1][Nt], 0, 0, 0);
      }
#pragma unroll
      for (int Nt = 0; Nt < 2; ++Nt) {
        acc[0][Nt] = __builtin_amdgcn_mfma_f32_32x32x16_f16(Ah0, Bl[Nt][ks],
                                                            acc[0][Nt], 0, 0, 0);
        acc[1][Nt] = __builtin_amdgcn_mfma_f32_32x32x16_f16(Ah1, Bl[Nt][ks],
                                                            acc[1][Nt], 0, 0, 0);
      }
    }
    // fold (ascending codes; strict > keeps first == np.argmin tie rule)
#pragma unroll
    for (int Mt = 0; Mt < 2; ++Mt)
#pragma unroll
      for (int reg = 0; reg < 16; ++reg) {
        int code = ti * 64 + Mt * 32 + (reg & 3) + 8 * (reg >> 2) + 4 * lhi;
#pragma unroll
        for (int Nt = 0; Nt < 2; ++Nt) {
          float v = acc[Mt][Nt][reg];
          if (v > bestv[Nt] || (v == bestv[Nt] && code < bestk[Nt])) {
            bestv[Nt] = v;
            bestk[Nt] = code;
          }
        }
      }
    __syncthreads();  // buf reads done; drains next-tile DMA (issued ~6K cyc ago)
  }

  // ---- epilogue: combine lhi halves (same row, disjoint codes)
#pragma unroll
  for (int Nt = 0; Nt < 2; ++Nt) {
    float v = bestv[Nt];
    int k = bestk[Nt];
    float ov = __shfl_xor(v, 32);
    int ok = __shfl_xor(k, 32);
    if (ov > v || (ov == v && ok < k)) { v = ov; k = ok; }
    if (lhi == 0) {
      int row = w * 64 + Nt * 32 + lr;
      bk_s[row] = k;
      aout[(size_t)blockIdx.x * 256 + row] = (float)k;
    }
  }
  __syncthreads();
  // gather winning codes (bit-exact f32 emb rows), 1KB-coalesced stores
  int kk0 = bk_s[l * 4], kk1 = bk_s[l * 4 + 1], kk2 = bk_s[l * 4 + 2],
      kk3 = bk_s[l * 4 + 3];
#pragma unroll 4
  for (int i = 0; i < 64; ++i) {
    int d = w * 64 + i;
    const float* er = emb + (size_t)d * K_DIM;
    float4 v = {er[kk0], er[kk1], er[kk2], er[kk3]};
    *(float4*)(out + ((size_t)b * D_DIM + d) * K_DIM + hw0 + l * 4) = v;
  }
}

extern "C" void kernel_launch(void* const* d_in, const int* in_sizes, int n_in,
                              void* d_out, int out_size, void* d_ws,
                              size_t ws_size, hipStream_t stream) {
  const float* x = (const float*)d_in[0];
  const float* emb = (const float*)d_in[1];
  float* out = (float*)d_out;
  float* aout = out + (size_t)64 * 256 * 32 * 32;  // 16777216
  float* nhp = (float*)d_ws;                       // 8*1024 f32 partial norms
  char* eimg_h = (char*)d_ws + 32768;              // 512 KiB
  char* eimg_l = eimg_h + 524288;                  // 512 KiB
  vq_prep<<<128, 256, 0, stream>>>(emb, nhp, eimg_h, eimg_l);
  vq_main<<<256, 256, 0, stream>>>(x, emb, nhp, eimg_h, eimg_l, out, aout);
}